// Round 2
// baseline (36825.085 us; speedup 1.0000x reference)
//
#include <hip/hip_runtime.h>
#include <cstdint>
#include <cstddef>

// ---------------------------------------------------------------------------
// PurifiedVAE persistent-RNN implementation.
// enc: persist_kernel<0>, 256 WGs = 4 chains (2 dir x 2 batch-halves) x 64 WGs.
// dec: persist_kernel<1>, 128 producer WGs (2 chains x 64) + 8 out-head WGs.
// Weights LDS-resident for all 512 steps; fp32 h master state in registers;
// h16 broadcast through global; per-(chain,step) device-scope counters for
// cross-WG ordering (release fence + atomicAdd / relaxed spin + acquire fence).
// ---------------------------------------------------------------------------

typedef _Float16 f16;
typedef _Float16 f16x8 __attribute__((ext_vector_type(8)));
typedef float f32x4 __attribute__((ext_vector_type(4)));

#define NB 256
#define NT 512
#define NI 12
#define NH 1024
#define NZ 128
#define NG 3072
#define KE_ENC 1056   // 1024 + 32 ext (x,1,pad)
#define KE_DEC 1184   // 1024 + 160 ext (x,1,pad,z128)
#define XK_ENC 32
#define XK_DEC 160

#define MFMA16(a, b, c) __builtin_amdgcn_mfma_f32_16x16x32_f16((a), (b), (c), 0, 0, 0)

// ---- workspace layout (bytes) ----
#define OFF_WMF   ((size_t)0)
#define OFF_WMB   (OFF_WMF + (size_t)NG * KE_ENC * 2)
#define OFF_WMD   (OFF_WMB + (size_t)NG * KE_ENC * 2)
#define OFF_WNF   (OFF_WMD + (size_t)NG * KE_DEC * 2)
#define OFF_WNB   (OFF_WNF + (size_t)NH * XK_ENC * 2)
#define OFF_WND   (OFF_WNB + (size_t)NH * XK_ENC * 2)
#define OFF_WOUT  (OFF_WND + (size_t)NH * XK_DEC * 2)
#define OFF_HENC16 (OFF_WOUT + (size_t)16 * KE_ENC * 2)   // [2 dir][2 buf][NB*NH] f16
#define OFF_HF32   (OFF_HENC16 + (size_t)4 * NB * NH * 2) // [2 dir][NB*NH] f32
#define OFF_HDEC16 (OFF_HF32 + (size_t)2 * NB * NH * 4)   // [2 buf][NB*NH] f16
#define OFF_H32D   (OFF_HDEC16 + (size_t)2 * NB * NH * 2) // [NB*NH] f32
#define OFF_Z32    (OFF_H32D + (size_t)NB * NH * 4)
#define OFF_Z16    (OFF_Z32 + (size_t)NB * NZ * 4)
#define OFF_CNT    (OFF_Z16 + (size_t)NB * NZ * 2)
// counters: cnt_enc 4*513 | cnt_dec 2*513 | cnt_out 2*512  = 4102 ints
#define N_CNT 4102
#define WS_NEEDED (OFF_CNT + (size_t)N_CNT * 4)

// d_out element offsets (fp32): recon [256,512,12], mean [256,128], stddev [256,128]
#define OUT_MEAN (NB * NT * NI)
#define OUT_STD  (OUT_MEAN + NB * NZ)

__device__ __forceinline__ void spin_ge(int* p, int target) {
    while (__hip_atomic_load(p, __ATOMIC_RELAXED, __HIP_MEMORY_SCOPE_AGENT) < target)
        __builtin_amdgcn_s_sleep(2);
}

// ---------------------------------------------------------------------------
// prep: build fp16 extended weight matrices, zero initial enc h16 buffers,
// init barrier counters.
// Extended layout per row c (gate-col):
//   k<1024          : W_hh[c][k]
//   k=1024+e, e<12  : W_ih[c][e]   (n-gate rows get zeros; i_n kept separate)
//   e==12           : bias (r,z: b_ih+b_hh ; n: b_hh only)
//   13<=e<32        : 0
//   e>=32 (dec)     : Wc_ih[c][12+e-32]  (z part; zero for n rows)
// WN (gi_n rows): [W_ih_n(12) | b_ih_n | 0 | z-part(dec)]
// WOUT rows i<12: [W_out[i][k<1024] | b_out at e==12]
// ---------------------------------------------------------------------------
__global__ __launch_bounds__(256) void prep_kernel(
    const float* __restrict__ Whhf, const float* __restrict__ Wihf,
    const float* __restrict__ bihf, const float* __restrict__ bhhf,
    const float* __restrict__ Whhb, const float* __restrict__ Wihb,
    const float* __restrict__ bihb, const float* __restrict__ bhhb,
    const float* __restrict__ Wchh, const float* __restrict__ Wcih,
    const float* __restrict__ bcih, const float* __restrict__ bchh,
    const float* __restrict__ Wo,   const float* __restrict__ bo,
    f16* __restrict__ wmf, f16* __restrict__ wmb, f16* __restrict__ wmd,
    f16* __restrict__ wnf, f16* __restrict__ wnb, f16* __restrict__ wnd,
    f16* __restrict__ wout,
    f16* __restrict__ h16e0f, f16* __restrict__ h16e0b,
    int* __restrict__ cntb)
{
    const int gsz = gridDim.x * blockDim.x;
    const int gid = blockIdx.x * blockDim.x + threadIdx.x;

    // encoder main (f and b together)
    for (int idx = gid; idx < NG * KE_ENC; idx += gsz) {
        const int c = idx / KE_ENC, k = idx - c * KE_ENC;
        float vf, vb;
        if (k < NH) { vf = Whhf[c * NH + k]; vb = Whhb[c * NH + k]; }
        else {
            const int e = k - NH;
            if (c < 2 * NH) {
                if (e < 12)       { vf = Wihf[c * 12 + e]; vb = Wihb[c * 12 + e]; }
                else if (e == 12) { vf = bihf[c] + bhhf[c]; vb = bihb[c] + bhhb[c]; }
                else              { vf = 0.f; vb = 0.f; }
            } else {
                vf = (e == 12) ? bhhf[c] : 0.f;
                vb = (e == 12) ? bhhb[c] : 0.f;
            }
        }
        wmf[idx] = (f16)vf; wmb[idx] = (f16)vb;
    }
    // decoder main
    for (int idx = gid; idx < NG * KE_DEC; idx += gsz) {
        const int c = idx / KE_DEC, k = idx - c * KE_DEC;
        float v;
        if (k < NH) v = Wchh[c * NH + k];
        else {
            const int e = k - NH;
            if (c < 2 * NH) {
                if (e < 12)       v = Wcih[c * 140 + e];
                else if (e == 12) v = bcih[c] + bchh[c];
                else if (e < 32)  v = 0.f;
                else              v = Wcih[c * 140 + 12 + (e - 32)];
            } else v = (e == 12) ? bchh[c] : 0.f;
        }
        wmd[idx] = (f16)v;
    }
    // encoder gi_n rows
    for (int idx = gid; idx < NH * XK_ENC; idx += gsz) {
        const int j = idx >> 5, e = idx & 31;
        const int c = 2 * NH + j;
        float vf, vb;
        if (e < 12)       { vf = Wihf[c * 12 + e]; vb = Wihb[c * 12 + e]; }
        else if (e == 12) { vf = bihf[c]; vb = bihb[c]; }
        else              { vf = 0.f; vb = 0.f; }
        wnf[idx] = (f16)vf; wnb[idx] = (f16)vb;
    }
    // decoder gi_n rows
    for (int idx = gid; idx < NH * XK_DEC; idx += gsz) {
        const int j = idx / XK_DEC, e = idx - j * XK_DEC;
        const int c = 2 * NH + j;
        float v;
        if (e < 12)       v = Wcih[c * 140 + e];
        else if (e == 12) v = bcih[c];
        else if (e < 32)  v = 0.f;
        else              v = Wcih[c * 140 + 12 + (e - 32)];
        wnd[idx] = (f16)v;
    }
    // out head
    for (int idx = gid; idx < 16 * KE_ENC; idx += gsz) {
        const int i = idx / KE_ENC, k = idx - i * KE_ENC;
        float v = 0.f;
        if (i < 12) {
            if (k < NH) v = Wo[i * NH + k];
            else if (k == NH + 12) v = bo[i];
        }
        wout[idx] = (f16)v;
    }
    // zero initial encoder h16 (buffer 0, both dirs)
    for (int idx = gid; idx < NB * NH; idx += gsz) {
        h16e0f[idx] = (f16)0.f; h16e0b[idx] = (f16)0.f;
    }
    // counters: cnt_enc[4][513] | cnt_dec[2][513] | cnt_out[2][512]
    for (int idx = gid; idx < N_CNT; idx += gsz) {
        int v = 0;
        if (idx < 2052)      { if (idx % 513 == 0) v = 64; }
        else if (idx < 3078) { if ((idx - 2052) % 513 == 0) v = 64; }
        cntb[idx] = v;
    }
}

// ---------------------------------------------------------------------------
// persist_kernel<MODE>: MODE 0 = encoder (grid 256), MODE 1 = decoder (grid 136).
// Producer WG: chain = bid>>6, slice = bid&63 -> 48 gate-cols {r,z,n} of 16
// h-cols, M=128 batch rows.  Waves M-split 32 rows (2 row-tiles).
// acc[g][rt] (g=r,z,n merged-ext), accn[rt] = gi_n (ext-K only).
// Out-head WGs (dec, bid>=128): 32 rows x 16 out-cols each, K=1056 wout.
// ---------------------------------------------------------------------------
template<int MODE>
__global__ __launch_bounds__(256) void persist_kernel(
    const float* __restrict__ x,
    const f16* __restrict__ wmF, const f16* __restrict__ wmB_,
    const f16* __restrict__ wnF, const f16* __restrict__ wnB_,
    const f16* __restrict__ wout, const f16* __restrict__ z16,
    f16* __restrict__ hbuf,          // enc: [dir][2][NB*NH]; dec: [2][NB*NH]
    float* __restrict__ hf32,        // enc final fp32 out [dir][NB*NH]
    const float* __restrict__ h32i,  // dec initial master (heads2)
    float* __restrict__ dout,
    int* __restrict__ cnt,           // enc 4*513 ; dec 2*513
    int* __restrict__ cnt_out)       // dec 2*512
{
    constexpr int KE  = MODE ? KE_DEC : KE_ENC;
    constexpr int KEP = KE + 8;
    constexpr int XK  = MODE ? XK_DEC : XK_ENC;
    constexpr int XKP = XK + 8;
    constexpr int NZT = MODE ? 4 : 0;   // z-register A k-tiles

    __shared__ f16 Wlds[48 * KEP];      // enc 102 KB / dec 114 KB
    __shared__ f16 Zx[128 * 40];        // per-step x+bias A-ext rows
    __shared__ f16 wnlds[16 * XKP];     // gi_n ext weights

    const int tid = threadIdx.x;
    const int bid = blockIdx.x;
    const int w = tid >> 6, lane = tid & 63;
    const int lr = lane & 15, quad = lane >> 4;

    if (MODE == 1 && bid >= 128) {
        // ---------------- out-head consumer WGs ----------------
        const int oc = bid - 128;                 // 0..7
        const int ochain = oc >> 2;
        const int mbase = ochain * 128 + (oc & 3) * 32;
        for (int u = tid; u < 16 * 132; u += 256) {
            const int r = u / 132, kk = u - r * 132;
            *(uint4*)&Wlds[r * 1064 + kk * 8] =
                *(const uint4*)(wout + (size_t)r * KE_ENC + kk * 8);
        }
        __syncthreads();
        if (w >= 2) return;                       // 2 active waves (16 rows each)
        const int rb = mbase + w * 16;
        f16x8 ax;                                 // A-ext: 1.0 at e==12
#pragma unroll
        for (int j = 0; j < 8; ++j) ax[j] = (f16)0.f;
        if (quad == 1) ax[4] = (f16)1.f;
        for (int t = 0; t < NT; ++t) {
            spin_ge(&cnt[ochain * 513 + t + 1], 64);
            __builtin_amdgcn_fence(__ATOMIC_ACQUIRE, "agent");
            const f16* hc = hbuf + (size_t)((t + 1) & 1) * (NB * NH);
            const f16* pA = hc + (size_t)(rb + lr) * NH + (quad << 3);
            f32x4 acc = {0.f, 0.f, 0.f, 0.f};
#pragma unroll 4
            for (int kt = 0; kt < 32; ++kt) {
                f16x8 a = *(const f16x8*)(pA + kt * 32);
                f16x8 b = *(const f16x8*)(&Wlds[lr * 1064 + kt * 32 + (quad << 3)]);
                acc = MFMA16(a, b, acc);
            }
            {
                f16x8 b = *(const f16x8*)(&Wlds[lr * 1064 + 1024 + (quad << 3)]);
                acc = MFMA16(ax, b, acc);
            }
            if (lr < NI) {
#pragma unroll
                for (int r = 0; r < 4; ++r) {
                    const int b_ = rb + quad * 4 + r;
                    dout[(size_t)b_ * (NT * NI) + t * NI + lr] =
                        1.f / (1.f + __expf(-acc[r]));
                }
            }
            if (lane == 0)
                __hip_atomic_fetch_add(&cnt_out[ochain * 512 + t], 1,
                                       __ATOMIC_RELAXED, __HIP_MEMORY_SCOPE_AGENT);
        }
        return;
    }

    // ---------------- producer WGs ----------------
    const int chain = bid >> 6;                 // enc 0..3, dec 0..1
    const int slice = bid & 63;
    const int dir = MODE ? 0 : (chain >> 1);
    const int m0 = MODE ? chain * 128 : (chain & 1) * 128;
    const int j0 = slice * 16;

    const f16* wm = (MODE == 0 && dir) ? wmB_ : wmF;
    const f16* wn = (MODE == 0 && dir) ? wnB_ : wnF;
    f16* hb0 = hbuf + (MODE ? (size_t)0 : (size_t)dir * 2 * NB * NH);

    // one-time weight load into LDS
    constexpr int KQ = KE / 8;
    for (int u = tid; u < 48 * KQ; u += 256) {
        const int r = u / KQ, kk = u - r * KQ;
        const int c = (r >> 4) * NH + j0 + (r & 15);
        *(uint4*)&Wlds[r * KEP + kk * 8] = *(const uint4*)(wm + (size_t)c * KE + kk * 8);
    }
    constexpr int XQ = XK / 8;
    for (int u = tid; u < 16 * XQ; u += 256) {
        const int r = u / XQ, kk = u - r * XQ;
        *(uint4*)&wnlds[r * XKP + kk * 8] =
            *(const uint4*)(wn + (size_t)(j0 + r) * XK + kk * 8);
    }
    __syncthreads();

    // register-resident fp32 h master + constant z A-fragments
    float hmast[2][4];
    f16x8 azr[2][NZT ? NZT : 1];
#pragma unroll
    for (int rt = 0; rt < 2; ++rt)
#pragma unroll
        for (int r = 0; r < 4; ++r)
            hmast[rt][r] = MODE
                ? h32i[(size_t)(m0 + (w << 5) + rt * 16 + quad * 4 + r) * NH + j0 + lr]
                : 0.f;
    if (MODE) {
#pragma unroll
        for (int rt = 0; rt < 2; ++rt)
#pragma unroll
            for (int zt = 0; zt < NZT; ++zt)
                azr[rt][zt] = *(const f16x8*)(z16 +
                    (size_t)(m0 + (w << 5) + rt * 16 + lr) * NZ + zt * 32 + (quad << 3));
    }

    const int zrow = tid >> 1, zhalf = tid & 1;
    const int rA0 = m0 + (w << 5) + lr;

    for (int t = 0; t < NT; ++t) {
        if (tid == 0) spin_ge(&cnt[chain * 513 + t], 64);
        __syncthreads();
        __builtin_amdgcn_fence(__ATOMIC_ACQUIRE, "agent");

        // stage per-step A-ext rows (x teacher / x_t, bias 1 at e==12)
        {
            const int b_ = m0 + zrow;
            const int tx = MODE ? (t - 1) : (dir ? (NT - 1 - t) : t);
#pragma unroll
            for (int e = zhalf * 20; e < zhalf * 20 + 20; ++e) {
                float v;
                if (e < NI) {
                    if (MODE == 1 && t == 0) v = (e == NI - 1) ? 1.f : 0.f;
                    else v = x[((size_t)b_ * NT + tx) * NI + e];
                } else v = (e == 12) ? 1.f : 0.f;
                Zx[zrow * 40 + e] = (f16)v;
            }
        }
        __syncthreads();

        const f16* hcur = hb0 + (size_t)(t & 1) * (NB * NH);
        const f16* pA = hcur + (size_t)rA0 * NH + (quad << 3);

        f32x4 acc[3][2], accn[2];
#pragma unroll
        for (int g = 0; g < 3; ++g)
#pragma unroll
            for (int rt = 0; rt < 2; ++rt) { f32x4 zv = {0.f,0.f,0.f,0.f}; acc[g][rt] = zv; }
        { f32x4 zv = {0.f,0.f,0.f,0.f}; accn[0] = zv; accn[1] = zv; }

        // main K loop: h16 global A, LDS-resident B
#pragma unroll 4
        for (int kt = 0; kt < 32; ++kt) {
            f16x8 a0 = *(const f16x8*)(pA + kt * 32);
            f16x8 a1 = *(const f16x8*)(pA + 16 * NH + kt * 32);
#pragma unroll
            for (int g = 0; g < 3; ++g) {
                f16x8 b = *(const f16x8*)(&Wlds[(g * 16 + lr) * KEP + kt * 32 + (quad << 3)]);
                acc[g][0] = MFMA16(a0, b, acc[g][0]);
                acc[g][1] = MFMA16(a1, b, acc[g][1]);
            }
        }
        // ext K tiles: xt=0 -> Zx (x,bias); xt>=1 -> z registers (dec)
#pragma unroll
        for (int xt = 0; xt <= NZT; ++xt) {
            const int kt = 32 + xt;
            f16x8 a0, a1;
            if (xt == 0) {
                a0 = *(const f16x8*)(&Zx[((w << 5) + lr) * 40 + (quad << 3)]);
                a1 = *(const f16x8*)(&Zx[((w << 5) + 16 + lr) * 40 + (quad << 3)]);
            } else { a0 = azr[0][xt - 1]; a1 = azr[1][xt - 1]; }
#pragma unroll
            for (int g = 0; g < 3; ++g) {
                f16x8 b = *(const f16x8*)(&Wlds[(g * 16 + lr) * KEP + kt * 32 + (quad << 3)]);
                acc[g][0] = MFMA16(a0, b, acc[g][0]);
                acc[g][1] = MFMA16(a1, b, acc[g][1]);
            }
            f16x8 bn = *(const f16x8*)(&wnlds[lr * XKP + xt * 32 + (quad << 3)]);
            accn[0] = MFMA16(a0, bn, accn[0]);
            accn[1] = MFMA16(a1, bn, accn[1]);
        }

        // protect ping-pong buffer from in-flight out-head readers (dec)
        if (MODE == 1 && t >= 2) {
            if (tid == 0) spin_ge(&cnt_out[chain * 512 + t - 2], 8);
            __syncthreads();
        }

        // gate combine + h update (fp32 master in registers)
        f16* hnext = hb0 + (size_t)((t + 1) & 1) * (NB * NH);
#pragma unroll
        for (int rt = 0; rt < 2; ++rt) {
#pragma unroll
            for (int r = 0; r < 4; ++r) {
                const float rr  = acc[0][rt][r];
                const float zz  = acc[1][rt][r];
                const float ghn = acc[2][rt][r];
                const float gin = accn[rt][r];
                const float rg = 1.f / (1.f + __expf(-rr));
                const float zg = 1.f / (1.f + __expf(-zz));
                const float nv = gin + rg * ghn;
                const float e2 = __expf(2.f * nv);
                const float th = 1.f - 2.f / (e2 + 1.f);   // tanh, inf-safe
                const float hn = (1.f - zg) * th + zg * hmast[rt][r];
                hmast[rt][r] = hn;
                const int row = m0 + (w << 5) + rt * 16 + quad * 4 + r;
                hnext[(size_t)row * NH + j0 + lr] = (f16)hn;
            }
        }
        __builtin_amdgcn_fence(__ATOMIC_RELEASE, "agent");
        __syncthreads();
        if (tid == 0)
            __hip_atomic_fetch_add(&cnt[chain * 513 + t + 1], 1,
                                   __ATOMIC_RELAXED, __HIP_MEMORY_SCOPE_AGENT);
    }

    if (MODE == 0) {
        float* hdst = hf32 + (size_t)dir * NB * NH;
#pragma unroll
        for (int rt = 0; rt < 2; ++rt)
#pragma unroll
            for (int r = 0; r < 4; ++r) {
                const int row = m0 + (w << 5) + rt * 16 + quad * 4 + r;
                hdst[(size_t)row * NH + j0 + lr] = hmast[rt][r];
            }
    }
}

// ---------------------------------------------------------------------------
// heads1: mean / stddev / z from final encoder states (fp32 exact).
// ---------------------------------------------------------------------------
__global__ __launch_bounds__(256) void heads1_kernel(
    const float* __restrict__ hf, const float* __restrict__ hb,
    const float* __restrict__ Wmu, const float* __restrict__ bmu,
    const float* __restrict__ Wvar, const float* __restrict__ bvar,
    const float* __restrict__ noise,
    float* __restrict__ dout, float* __restrict__ z32, f16* __restrict__ z16)
{
    const int tid = threadIdx.x;
    const int b  = ((int)blockIdx.x >> 3) * 16 + (tid >> 4);
    const int zi = ((int)blockIdx.x & 7) * 16 + (tid & 15);
    const float4* h4 = (const float4*)(hf + (size_t)b * NH);
    const float4* g4 = (const float4*)(hb + (size_t)b * NH);
    const float4* m4 = (const float4*)(Wmu + (size_t)zi * (2 * NH));
    const float4* v4 = (const float4*)(Wvar + (size_t)zi * (2 * NH));
    float sm_ = 0.f, sv = 0.f;
    for (int k = 0; k < NH / 4; ++k) {
        const float4 h = h4[k], a = m4[k], c = v4[k];
        sm_ += h.x * a.x + h.y * a.y + h.z * a.z + h.w * a.w;
        sv  += h.x * c.x + h.y * c.y + h.z * c.z + h.w * c.w;
    }
    for (int k = 0; k < NH / 4; ++k) {
        const float4 h = g4[k], a = m4[NH / 4 + k], c = v4[NH / 4 + k];
        sm_ += h.x * a.x + h.y * a.y + h.z * a.z + h.w * a.w;
        sv  += h.x * c.x + h.y * c.y + h.z * c.z + h.w * c.w;
    }
    const float mean = sm_ + bmu[zi];
    const float lv   = sv + bvar[zi];
    const float sd   = __expf(0.5f * lv);
    const float zv   = mean + sd * noise[(size_t)b * NZ + zi];
    dout[OUT_MEAN + (size_t)b * NZ + zi] = mean;
    dout[OUT_STD  + (size_t)b * NZ + zi] = sd;
    z32[b * NZ + zi] = zv;
    z16[b * NZ + zi] = (f16)zv;
}

// ---------------------------------------------------------------------------
// heads2: h_dec0 = tanh(z @ W_init^T + b_init) -> fp32 master + h16 buffer 0.
// ---------------------------------------------------------------------------
__global__ __launch_bounds__(256) void heads2_kernel(
    const float* __restrict__ z32, const float* __restrict__ Winit,
    const float* __restrict__ binit,
    float* __restrict__ h32d, f16* __restrict__ h16d)
{
    __shared__ float Wi[16 * NZ];
    __shared__ float bi[16];
    const int tid = threadIdx.x;
    const int jb = blockIdx.x;
    for (int f = tid; f < 16 * NZ; f += 256)
        Wi[f] = Winit[(size_t)(jb * 16 + (f >> 7)) * NZ + (f & 127)];
    if (tid < 16) bi[tid] = binit[jb * 16 + tid];
    __syncthreads();
    const int b = tid;
    const float4* z4 = (const float4*)(z32 + (size_t)b * NZ);
    float4 zr[NZ / 4];
#pragma unroll
    for (int k = 0; k < NZ / 4; ++k) zr[k] = z4[k];
    for (int hj = 0; hj < 16; ++hj) {
        const float4* w4 = (const float4*)(Wi + hj * NZ);
        float s = bi[hj];
#pragma unroll
        for (int k = 0; k < NZ / 4; ++k) {
            const float4 a = w4[k], z = zr[k];
            s += z.x * a.x + z.y * a.y + z.z * a.z + z.w * a.w;
        }
        const float e2 = __expf(2.f * s);
        const float th = 1.f - 2.f / (e2 + 1.f);
        h32d[(size_t)b * NH + jb * 16 + hj] = th;
        h16d[(size_t)b * NH + jb * 16 + hj] = (f16)th;
    }
}

// ---------------------------------------------------------------------------
extern "C" void kernel_launch(void* const* d_in, const int* in_sizes, int n_in,
                              void* d_out, int out_size, void* d_ws, size_t ws_size,
                              hipStream_t stream)
{
    const float* x     = (const float*)d_in[0];
    const float* noise = (const float*)d_in[1];
    const float* Wihf  = (const float*)d_in[2];
    const float* Whhf  = (const float*)d_in[3];
    const float* bihf  = (const float*)d_in[4];
    const float* bhhf  = (const float*)d_in[5];
    const float* Wihb  = (const float*)d_in[6];
    const float* Whhb  = (const float*)d_in[7];
    const float* bihb  = (const float*)d_in[8];
    const float* bhhb  = (const float*)d_in[9];
    const float* Wmu   = (const float*)d_in[10];
    const float* bmu   = (const float*)d_in[11];
    const float* Wvar  = (const float*)d_in[12];
    const float* bvar  = (const float*)d_in[13];
    const float* Winit = (const float*)d_in[14];
    const float* binit = (const float*)d_in[15];
    const float* Wo    = (const float*)d_in[16];
    const float* bo    = (const float*)d_in[17];
    const float* Wcih  = (const float*)d_in[18];
    const float* Wchh  = (const float*)d_in[19];
    const float* bcih  = (const float*)d_in[20];
    const float* bchh  = (const float*)d_in[21];
    float* dout = (float*)d_out;
    char*  ws   = (char*)d_ws;

    if (ws_size < WS_NEEDED) return;  // ~27.3 MB required

    f16* wmf  = (f16*)(ws + OFF_WMF);
    f16* wmb  = (f16*)(ws + OFF_WMB);
    f16* wmd  = (f16*)(ws + OFF_WMD);
    f16* wnf  = (f16*)(ws + OFF_WNF);
    f16* wnb  = (f16*)(ws + OFF_WNB);
    f16* wnd  = (f16*)(ws + OFF_WND);
    f16* wo16 = (f16*)(ws + OFF_WOUT);
    f16* henc16  = (f16*)(ws + OFF_HENC16);   // [dir][buf][NB*NH]
    float* hf32  = (float*)(ws + OFF_HF32);   // [dir][NB*NH]
    f16* hdec16  = (f16*)(ws + OFF_HDEC16);   // [buf][NB*NH]
    float* h32d  = (float*)(ws + OFF_H32D);
    float* z32p  = (float*)(ws + OFF_Z32);
    f16*   z16p  = (f16*)(ws + OFF_Z16);
    int*   cntb  = (int*)(ws + OFF_CNT);
    int* cnt_enc = cntb;
    int* cnt_dec = cntb + 2052;
    int* cnt_out = cntb + 3078;

    prep_kernel<<<2048, 256, 0, stream>>>(
        Whhf, Wihf, bihf, bhhf, Whhb, Wihb, bihb, bhhb,
        Wchh, Wcih, bcih, bchh, Wo, bo,
        wmf, wmb, wmd, wnf, wnb, wnd, wo16,
        henc16 /*dir0 buf0*/, henc16 + (size_t)2 * NB * NH /*dir1 buf0*/,
        cntb);

    // encoder: 512 steps in one persistent launch
    persist_kernel<0><<<256, 256, 0, stream>>>(
        x, wmf, wmb, wnf, wnb, (const f16*)nullptr, (const f16*)nullptr,
        henc16, hf32, (const float*)nullptr, dout, cnt_enc, (int*)nullptr);

    heads1_kernel<<<128, 256, 0, stream>>>(hf32, hf32 + (size_t)NB * NH,
                                           Wmu, bmu, Wvar, bvar, noise,
                                           dout, z32p, z16p);
    heads2_kernel<<<64, 256, 0, stream>>>(z32p, Winit, binit, h32d, hdec16);

    // decoder: 512 steps + fused sigmoid out-head in one persistent launch
    persist_kernel<1><<<136, 256, 0, stream>>>(
        x, wmd, (const f16*)nullptr, wnd, (const f16*)nullptr, wo16, z16p,
        hdec16, (float*)nullptr, h32d, dout, cnt_dec, cnt_out);
}

// Round 3
// 33433.026 us; speedup vs baseline: 1.1015x; 1.1015x over previous
//
#include <hip/hip_runtime.h>
#include <cstdint>
#include <cstddef>

// ---------------------------------------------------------------------------
// PurifiedVAE persistent-RNN, fence-free cross-WG communication.
// enc: persist_kernel<0>, 256 WGs = 4 chains (2 dir x 2 batch-halves) x 64 WGs.
// dec: persist_kernel<1>, 128 producer WGs (2 chains x 64) + 8 out-head WGs.
// Weights LDS-resident for all 512 steps; fp32 h master state in registers.
// h16 state crosses WGs via device-scope (agent) relaxed atomics: stores are
// write-through (sc0 sc1) to LLC, loads bypass L1/L2 -- NO buffer_wbl2 /
// buffer_inv fences in the step loop (those caused the round-2 regression).
// Flag ordering: __syncthreads() drains vmcnt(0) before tid0's relaxed add.
// ---------------------------------------------------------------------------

typedef _Float16 f16;
typedef _Float16 f16x8 __attribute__((ext_vector_type(8)));
typedef float f32x4 __attribute__((ext_vector_type(4)));

#define NB 256
#define NT 512
#define NI 12
#define NH 1024
#define NZ 128
#define NG 3072
#define KE_ENC 1056   // 1024 + 32 ext (x,1,pad)
#define KE_DEC 1184   // 1024 + 160 ext (x,1,pad,z128)
#define XK_ENC 32
#define XK_DEC 160

#define MFMA16(a, b, c) __builtin_amdgcn_mfma_f32_16x16x32_f16((a), (b), (c), 0, 0, 0)

// ---- workspace layout (bytes) ----
#define OFF_WMF   ((size_t)0)
#define OFF_WMB   (OFF_WMF + (size_t)NG * KE_ENC * 2)
#define OFF_WMD   (OFF_WMB + (size_t)NG * KE_ENC * 2)
#define OFF_WNF   (OFF_WMD + (size_t)NG * KE_DEC * 2)
#define OFF_WNB   (OFF_WNF + (size_t)NH * XK_ENC * 2)
#define OFF_WND   (OFF_WNB + (size_t)NH * XK_ENC * 2)
#define OFF_WOUT  (OFF_WND + (size_t)NH * XK_DEC * 2)
#define OFF_HENC16 (OFF_WOUT + (size_t)16 * KE_ENC * 2)   // [2 dir][2 buf][NB*NH] f16
#define OFF_HF32   (OFF_HENC16 + (size_t)4 * NB * NH * 2) // [2 dir][NB*NH] f32
#define OFF_HDEC16 (OFF_HF32 + (size_t)2 * NB * NH * 4)   // [2 buf][NB*NH] f16
#define OFF_H32D   (OFF_HDEC16 + (size_t)2 * NB * NH * 2) // [NB*NH] f32
#define OFF_Z32    (OFF_H32D + (size_t)NB * NH * 4)
#define OFF_Z16    (OFF_Z32 + (size_t)NB * NZ * 4)
#define OFF_CNT    (OFF_Z16 + (size_t)NB * NZ * 2)
// counters: cnt_enc 4*513 | cnt_dec 2*513 | cnt_out 2*512  = 4102 ints
#define N_CNT 4102
#define WS_NEEDED (OFF_CNT + (size_t)N_CNT * 4)

// d_out element offsets (fp32): recon [256,512,12], mean [256,128], stddev [256,128]
#define OUT_MEAN (NB * NT * NI)
#define OUT_STD  (OUT_MEAN + NB * NZ)

__device__ __forceinline__ void spin_ge(int* p, int target) {
    while (__hip_atomic_load(p, __ATOMIC_RELAXED, __HIP_MEMORY_SCOPE_AGENT) < target)
        __builtin_amdgcn_s_sleep(2);
}

// coherent 16-B A-fragment load: 4x dword agent-scope relaxed atomic loads
// (lower to global_load_dword sc0 sc1 -> forced L1/L2 miss, served from LLC;
// normal vmcnt tracking so loads pipeline).
__device__ __forceinline__ f16x8 ld_a16(const f16* p) {
    const unsigned* q = (const unsigned*)p;
    uint4 v;
    v.x = __hip_atomic_load(q + 0, __ATOMIC_RELAXED, __HIP_MEMORY_SCOPE_AGENT);
    v.y = __hip_atomic_load(q + 1, __ATOMIC_RELAXED, __HIP_MEMORY_SCOPE_AGENT);
    v.z = __hip_atomic_load(q + 2, __ATOMIC_RELAXED, __HIP_MEMORY_SCOPE_AGENT);
    v.w = __hip_atomic_load(q + 3, __ATOMIC_RELAXED, __HIP_MEMORY_SCOPE_AGENT);
    return __builtin_bit_cast(f16x8, v);
}

// ---------------------------------------------------------------------------
// prep: build fp16 extended weight matrices, zero initial enc h16 buffers,
// init barrier counters. (layout comments: see round-1 source; unchanged)
// ---------------------------------------------------------------------------
__global__ __launch_bounds__(256) void prep_kernel(
    const float* __restrict__ Whhf, const float* __restrict__ Wihf,
    const float* __restrict__ bihf, const float* __restrict__ bhhf,
    const float* __restrict__ Whhb, const float* __restrict__ Wihb,
    const float* __restrict__ bihb, const float* __restrict__ bhhb,
    const float* __restrict__ Wchh, const float* __restrict__ Wcih,
    const float* __restrict__ bcih, const float* __restrict__ bchh,
    const float* __restrict__ Wo,   const float* __restrict__ bo,
    f16* __restrict__ wmf, f16* __restrict__ wmb, f16* __restrict__ wmd,
    f16* __restrict__ wnf, f16* __restrict__ wnb, f16* __restrict__ wnd,
    f16* __restrict__ wout,
    f16* __restrict__ h16e0f, f16* __restrict__ h16e0b,
    int* __restrict__ cntb)
{
    const int gsz = gridDim.x * blockDim.x;
    const int gid = blockIdx.x * blockDim.x + threadIdx.x;

    for (int idx = gid; idx < NG * KE_ENC; idx += gsz) {
        const int c = idx / KE_ENC, k = idx - c * KE_ENC;
        float vf, vb;
        if (k < NH) { vf = Whhf[c * NH + k]; vb = Whhb[c * NH + k]; }
        else {
            const int e = k - NH;
            if (c < 2 * NH) {
                if (e < 12)       { vf = Wihf[c * 12 + e]; vb = Wihb[c * 12 + e]; }
                else if (e == 12) { vf = bihf[c] + bhhf[c]; vb = bihb[c] + bhhb[c]; }
                else              { vf = 0.f; vb = 0.f; }
            } else {
                vf = (e == 12) ? bhhf[c] : 0.f;
                vb = (e == 12) ? bhhb[c] : 0.f;
            }
        }
        wmf[idx] = (f16)vf; wmb[idx] = (f16)vb;
    }
    for (int idx = gid; idx < NG * KE_DEC; idx += gsz) {
        const int c = idx / KE_DEC, k = idx - c * KE_DEC;
        float v;
        if (k < NH) v = Wchh[c * NH + k];
        else {
            const int e = k - NH;
            if (c < 2 * NH) {
                if (e < 12)       v = Wcih[c * 140 + e];
                else if (e == 12) v = bcih[c] + bchh[c];
                else if (e < 32)  v = 0.f;
                else              v = Wcih[c * 140 + 12 + (e - 32)];
            } else v = (e == 12) ? bchh[c] : 0.f;
        }
        wmd[idx] = (f16)v;
    }
    for (int idx = gid; idx < NH * XK_ENC; idx += gsz) {
        const int j = idx >> 5, e = idx & 31;
        const int c = 2 * NH + j;
        float vf, vb;
        if (e < 12)       { vf = Wihf[c * 12 + e]; vb = Wihb[c * 12 + e]; }
        else if (e == 12) { vf = bihf[c]; vb = bihb[c]; }
        else              { vf = 0.f; vb = 0.f; }
        wnf[idx] = (f16)vf; wnb[idx] = (f16)vb;
    }
    for (int idx = gid; idx < NH * XK_DEC; idx += gsz) {
        const int j = idx / XK_DEC, e = idx - j * XK_DEC;
        const int c = 2 * NH + j;
        float v;
        if (e < 12)       v = Wcih[c * 140 + e];
        else if (e == 12) v = bcih[c];
        else if (e < 32)  v = 0.f;
        else              v = Wcih[c * 140 + 12 + (e - 32)];
        wnd[idx] = (f16)v;
    }
    for (int idx = gid; idx < 16 * KE_ENC; idx += gsz) {
        const int i = idx / KE_ENC, k = idx - i * KE_ENC;
        float v = 0.f;
        if (i < 12) {
            if (k < NH) v = Wo[i * NH + k];
            else if (k == NH + 12) v = bo[i];
        }
        wout[idx] = (f16)v;
    }
    for (int idx = gid; idx < NB * NH; idx += gsz) {
        h16e0f[idx] = (f16)0.f; h16e0b[idx] = (f16)0.f;
    }
    // counters: cnt_enc[4][513] | cnt_dec[2][513] | cnt_out[2][512]
    for (int idx = gid; idx < N_CNT; idx += gsz) {
        int v = 0;
        if (idx < 2052)      { if (idx % 513 == 0) v = 64; }
        else if (idx < 3078) { if ((idx - 2052) % 513 == 0) v = 64; }
        cntb[idx] = v;
    }
}

// ---------------------------------------------------------------------------
// persist_kernel<MODE>: MODE 0 = encoder (grid 256), MODE 1 = decoder (grid 136).
// Producer WG: chain = bid>>6, slice = bid&63 -> 48 gate-cols {r,z,n} of 16
// h-cols, M=128 batch rows.  Waves M-split 32 rows (2 row-tiles).
// Out-head WGs (dec, bid>=128): 32 rows x 16 out-cols each, K=1056 wout.
// ---------------------------------------------------------------------------
template<int MODE>
__global__ __launch_bounds__(256) void persist_kernel(
    const float* __restrict__ x,
    const f16* __restrict__ wmF, const f16* __restrict__ wmB_,
    const f16* __restrict__ wnF, const f16* __restrict__ wnB_,
    const f16* __restrict__ wout, const f16* __restrict__ z16,
    f16* __restrict__ hbuf,          // enc: [dir][2][NB*NH]; dec: [2][NB*NH]
    float* __restrict__ hf32,        // enc final fp32 out [dir][NB*NH]
    const float* __restrict__ h32i,  // dec initial master (heads2)
    float* __restrict__ dout,
    int* __restrict__ cnt,           // enc 4*513 ; dec 2*513
    int* __restrict__ cnt_out)       // dec 2*512
{
    constexpr int KE  = MODE ? KE_DEC : KE_ENC;
    constexpr int KEP = KE + 8;
    constexpr int XK  = MODE ? XK_DEC : XK_ENC;
    constexpr int XKP = XK + 8;
    constexpr int NZT = MODE ? 4 : 0;   // z-register A k-tiles

    __shared__ f16 Wlds[48 * KEP];      // enc 102 KB / dec 114 KB
    __shared__ f16 Zx[128 * 40];        // per-step x+bias A-ext rows
    __shared__ f16 wnlds[16 * XKP];     // gi_n ext weights

    const int tid = threadIdx.x;
    const int bid = blockIdx.x;
    const int w = tid >> 6, lane = tid & 63;
    const int lr = lane & 15, quad = lane >> 4;

    if (MODE == 1 && bid >= 128) {
        // ---------------- out-head consumer WGs ----------------
        const int oc = bid - 128;                 // 0..7
        const int ochain = oc >> 2;
        const int mbase = ochain * 128 + (oc & 3) * 32;
        for (int u = tid; u < 16 * 132; u += 256) {
            const int r = u / 132, kk = u - r * 132;
            *(uint4*)&Wlds[r * 1064 + kk * 8] =
                *(const uint4*)(wout + (size_t)r * KE_ENC + kk * 8);
        }
        __syncthreads();
        if (w >= 2) return;                       // 2 active waves (16 rows each)
        const int rb = mbase + w * 16;
        f16x8 ax;                                 // A-ext: 1.0 at e==12
#pragma unroll
        for (int j = 0; j < 8; ++j) ax[j] = (f16)0.f;
        if (quad == 1) ax[4] = (f16)1.f;
        for (int t = 0; t < NT; ++t) {
            spin_ge(&cnt[ochain * 513 + t + 1], 64);
            const f16* hc = hbuf + (size_t)((t + 1) & 1) * (NB * NH);
            const f16* pA = hc + (size_t)(rb + lr) * NH + (quad << 3);
            f32x4 acc = {0.f, 0.f, 0.f, 0.f};
#pragma unroll 4
            for (int kt = 0; kt < 32; ++kt) {
                f16x8 a = ld_a16(pA + kt * 32);
                f16x8 b = *(const f16x8*)(&Wlds[lr * 1064 + kt * 32 + (quad << 3)]);
                acc = MFMA16(a, b, acc);
            }
            {
                f16x8 b = *(const f16x8*)(&Wlds[lr * 1064 + 1024 + (quad << 3)]);
                acc = MFMA16(ax, b, acc);
            }
            if (lr < NI) {
#pragma unroll
                for (int r = 0; r < 4; ++r) {
                    const int b_ = rb + quad * 4 + r;
                    dout[(size_t)b_ * (NT * NI) + t * NI + lr] =
                        1.f / (1.f + __expf(-acc[r]));
                }
            }
            // reads complete (acc consumed); signal buffer free
            if (lane == 0)
                __hip_atomic_fetch_add(&cnt_out[ochain * 512 + t], 1,
                                       __ATOMIC_RELAXED, __HIP_MEMORY_SCOPE_AGENT);
        }
        return;
    }

    // ---------------- producer WGs ----------------
    const int chain = bid >> 6;                 // enc 0..3, dec 0..1
    const int slice = bid & 63;
    const int dir = MODE ? 0 : (chain >> 1);
    const int m0 = MODE ? chain * 128 : (chain & 1) * 128;
    const int j0 = slice * 16;

    const f16* wm = (MODE == 0 && dir) ? wmB_ : wmF;
    const f16* wn = (MODE == 0 && dir) ? wnB_ : wnF;
    f16* hb0 = hbuf + (MODE ? (size_t)0 : (size_t)dir * 2 * NB * NH);

    // one-time weight load into LDS + Zx zero-init (e>=16 region stays 0)
    constexpr int KQ = KE / 8;
    for (int u = tid; u < 48 * KQ; u += 256) {
        const int r = u / KQ, kk = u - r * KQ;
        const int c = (r >> 4) * NH + j0 + (r & 15);
        *(uint4*)&Wlds[r * KEP + kk * 8] = *(const uint4*)(wm + (size_t)c * KE + kk * 8);
    }
    constexpr int XQ = XK / 8;
    for (int u = tid; u < 16 * XQ; u += 256) {
        const int r = u / XQ, kk = u - r * XQ;
        *(uint4*)&wnlds[r * XKP + kk * 8] =
            *(const uint4*)(wn + (size_t)(j0 + r) * XK + kk * 8);
    }
    for (int u = tid; u < 128 * 40 / 8; u += 256)
        *(uint4*)&Zx[u * 8] = make_uint4(0u, 0u, 0u, 0u);
    __syncthreads();

    // register-resident fp32 h master + constant z A-fragments
    float hmast[2][4];
    f16x8 azr[2][NZT ? NZT : 1];
#pragma unroll
    for (int rt = 0; rt < 2; ++rt)
#pragma unroll
        for (int r = 0; r < 4; ++r)
            hmast[rt][r] = MODE
                ? h32i[(size_t)(m0 + (w << 5) + rt * 16 + quad * 4 + r) * NH + j0 + lr]
                : 0.f;
    if (MODE) {
#pragma unroll
        for (int rt = 0; rt < 2; ++rt)
#pragma unroll
            for (int zt = 0; zt < NZT; ++zt)
                azr[rt][zt] = *(const f16x8*)(z16 +
                    (size_t)(m0 + (w << 5) + rt * 16 + lr) * NZ + zt * 32 + (quad << 3));
    }

    const int rA0 = m0 + (w << 5) + lr;

    for (int t = 0; t < NT; ++t) {
        if (tid == 0) spin_ge(&cnt[chain * 513 + t], 64);
        __syncthreads();

        // stage per-step A-ext rows: one thread per batch row, 16 f16 packed
        // as two ds_write_b128 (row stride 40 halves = 20 dwords: conflict-free)
        if (tid < 128) {
            f16 rowv[16];
            if (MODE == 1 && t == 0) {
#pragma unroll
                for (int e = 0; e < 12; ++e) rowv[e] = (f16)((e == NI - 1) ? 1.f : 0.f);
            } else {
                const int b_ = m0 + tid;
                const int tx = MODE ? (t - 1) : (dir ? (NT - 1 - t) : t);
                const float4* xr = (const float4*)(x + ((size_t)b_ * NT + tx) * NI);
                const float4 x0 = xr[0], x1 = xr[1], x2 = xr[2];
                rowv[0] = (f16)x0.x; rowv[1] = (f16)x0.y; rowv[2] = (f16)x0.z; rowv[3] = (f16)x0.w;
                rowv[4] = (f16)x1.x; rowv[5] = (f16)x1.y; rowv[6] = (f16)x1.z; rowv[7] = (f16)x1.w;
                rowv[8] = (f16)x2.x; rowv[9] = (f16)x2.y; rowv[10] = (f16)x2.z; rowv[11] = (f16)x2.w;
            }
            rowv[12] = (f16)1.f; rowv[13] = (f16)0.f; rowv[14] = (f16)0.f; rowv[15] = (f16)0.f;
            *(uint4*)&Zx[tid * 40]     = *(const uint4*)&rowv[0];
            *(uint4*)&Zx[tid * 40 + 8] = *(const uint4*)&rowv[8];
        }
        __syncthreads();

        const f16* hcur = hb0 + (size_t)(t & 1) * (NB * NH);
        const f16* pA = hcur + (size_t)rA0 * NH + (quad << 3);

        f32x4 acc[3][2], accn[2];
#pragma unroll
        for (int g = 0; g < 3; ++g)
#pragma unroll
            for (int rt = 0; rt < 2; ++rt) { f32x4 zv = {0.f,0.f,0.f,0.f}; acc[g][rt] = zv; }
        { f32x4 zv = {0.f,0.f,0.f,0.f}; accn[0] = zv; accn[1] = zv; }

        // main K loop: coherent h16 A-loads (LLC), LDS-resident B
#pragma unroll 4
        for (int kt = 0; kt < 32; ++kt) {
            f16x8 a0 = ld_a16(pA + kt * 32);
            f16x8 a1 = ld_a16(pA + 16 * NH + kt * 32);
#pragma unroll
            for (int g = 0; g < 3; ++g) {
                f16x8 b = *(const f16x8*)(&Wlds[(g * 16 + lr) * KEP + kt * 32 + (quad << 3)]);
                acc[g][0] = MFMA16(a0, b, acc[g][0]);
                acc[g][1] = MFMA16(a1, b, acc[g][1]);
            }
        }
        // ext K tiles: xt=0 -> Zx (x,bias); xt>=1 -> z registers (dec)
#pragma unroll
        for (int xt = 0; xt <= NZT; ++xt) {
            const int kt = 32 + xt;
            f16x8 a0, a1;
            if (xt == 0) {
                a0 = *(const f16x8*)(&Zx[((w << 5) + lr) * 40 + (quad << 3)]);
                a1 = *(const f16x8*)(&Zx[((w << 5) + 16 + lr) * 40 + (quad << 3)]);
            } else { a0 = azr[0][xt - 1]; a1 = azr[1][xt - 1]; }
#pragma unroll
            for (int g = 0; g < 3; ++g) {
                f16x8 b = *(const f16x8*)(&Wlds[(g * 16 + lr) * KEP + kt * 32 + (quad << 3)]);
                acc[g][0] = MFMA16(a0, b, acc[g][0]);
                acc[g][1] = MFMA16(a1, b, acc[g][1]);
            }
            f16x8 bn = *(const f16x8*)(&wnlds[lr * XKP + xt * 32 + (quad << 3)]);
            accn[0] = MFMA16(a0, bn, accn[0]);
            accn[1] = MFMA16(a1, bn, accn[1]);
        }

        // protect ping-pong buffer from in-flight out-head readers (dec)
        if (MODE == 1 && t >= 2) {
            if (tid == 0) spin_ge(&cnt_out[chain * 512 + t - 2], 8);
            __syncthreads();
        }

        // gate combine + h update (fp32 master in registers); h16 published
        // via packed write-through dword stores (column pairs via shfl_xor)
        f16* hnext = hb0 + (size_t)((t + 1) & 1) * (NB * NH);
#pragma unroll
        for (int rt = 0; rt < 2; ++rt) {
#pragma unroll
            for (int r = 0; r < 4; ++r) {
                const float rr  = acc[0][rt][r];
                const float zz  = acc[1][rt][r];
                const float ghn = acc[2][rt][r];
                const float gin = accn[rt][r];
                const float rg = 1.f / (1.f + __expf(-rr));
                const float zg = 1.f / (1.f + __expf(-zz));
                const float nv = gin + rg * ghn;
                const float e2 = __expf(2.f * nv);
                const float th = 1.f - 2.f / (e2 + 1.f);   // tanh, inf-safe
                const float hn = (1.f - zg) * th + zg * hmast[rt][r];
                hmast[rt][r] = hn;
                const unsigned hv =
                    (unsigned)__builtin_bit_cast(unsigned short, (f16)hn);
                const unsigned ov = (unsigned)__shfl_xor((int)hv, 1, 64);
                if (!(lr & 1)) {
                    const int row = m0 + (w << 5) + rt * 16 + quad * 4 + r;
                    __hip_atomic_store(
                        (unsigned*)&hnext[(size_t)row * NH + j0 + lr],
                        hv | (ov << 16),
                        __ATOMIC_RELAXED, __HIP_MEMORY_SCOPE_AGENT);
                }
            }
        }
        __syncthreads();   // vmcnt(0) drain of all waves' stores before flag
        if (tid == 0)
            __hip_atomic_fetch_add(&cnt[chain * 513 + t + 1], 1,
                                   __ATOMIC_RELAXED, __HIP_MEMORY_SCOPE_AGENT);
    }

    if (MODE == 0) {
        float* hdst = hf32 + (size_t)dir * NB * NH;
#pragma unroll
        for (int rt = 0; rt < 2; ++rt)
#pragma unroll
            for (int r = 0; r < 4; ++r) {
                const int row = m0 + (w << 5) + rt * 16 + quad * 4 + r;
                hdst[(size_t)row * NH + j0 + lr] = hmast[rt][r];
            }
    }
}

// ---------------------------------------------------------------------------
// heads1: mean / stddev / z from final encoder states (fp32 exact).
// ---------------------------------------------------------------------------
__global__ __launch_bounds__(256) void heads1_kernel(
    const float* __restrict__ hf, const float* __restrict__ hb,
    const float* __restrict__ Wmu, const float* __restrict__ bmu,
    const float* __restrict__ Wvar, const float* __restrict__ bvar,
    const float* __restrict__ noise,
    float* __restrict__ dout, float* __restrict__ z32, f16* __restrict__ z16)
{
    const int tid = threadIdx.x;
    const int b  = ((int)blockIdx.x >> 3) * 16 + (tid >> 4);
    const int zi = ((int)blockIdx.x & 7) * 16 + (tid & 15);
    const float4* h4 = (const float4*)(hf + (size_t)b * NH);
    const float4* g4 = (const float4*)(hb + (size_t)b * NH);
    const float4* m4 = (const float4*)(Wmu + (size_t)zi * (2 * NH));
    const float4* v4 = (const float4*)(Wvar + (size_t)zi * (2 * NH));
    float sm_ = 0.f, sv = 0.f;
    for (int k = 0; k < NH / 4; ++k) {
        const float4 h = h4[k], a = m4[k], c = v4[k];
        sm_ += h.x * a.x + h.y * a.y + h.z * a.z + h.w * a.w;
        sv  += h.x * c.x + h.y * c.y + h.z * c.z + h.w * c.w;
    }
    for (int k = 0; k < NH / 4; ++k) {
        const float4 h = g4[k], a = m4[NH / 4 + k], c = v4[NH / 4 + k];
        sm_ += h.x * a.x + h.y * a.y + h.z * a.z + h.w * a.w;
        sv  += h.x * c.x + h.y * c.y + h.z * c.z + h.w * c.w;
    }
    const float mean = sm_ + bmu[zi];
    const float lv   = sv + bvar[zi];
    const float sd   = __expf(0.5f * lv);
    const float zv   = mean + sd * noise[(size_t)b * NZ + zi];
    dout[OUT_MEAN + (size_t)b * NZ + zi] = mean;
    dout[OUT_STD  + (size_t)b * NZ + zi] = sd;
    z32[b * NZ + zi] = zv;
    z16[b * NZ + zi] = (f16)zv;
}

// ---------------------------------------------------------------------------
// heads2: h_dec0 = tanh(z @ W_init^T + b_init) -> fp32 master + h16 buffer 0.
// ---------------------------------------------------------------------------
__global__ __launch_bounds__(256) void heads2_kernel(
    const float* __restrict__ z32, const float* __restrict__ Winit,
    const float* __restrict__ binit,
    float* __restrict__ h32d, f16* __restrict__ h16d)
{
    __shared__ float Wi[16 * NZ];
    __shared__ float bi[16];
    const int tid = threadIdx.x;
    const int jb = blockIdx.x;
    for (int f = tid; f < 16 * NZ; f += 256)
        Wi[f] = Winit[(size_t)(jb * 16 + (f >> 7)) * NZ + (f & 127)];
    if (tid < 16) bi[tid] = binit[jb * 16 + tid];
    __syncthreads();
    const int b = tid;
    const float4* z4 = (const float4*)(z32 + (size_t)b * NZ);
    float4 zr[NZ / 4];
#pragma unroll
    for (int k = 0; k < NZ / 4; ++k) zr[k] = z4[k];
    for (int hj = 0; hj < 16; ++hj) {
        const float4* w4 = (const float4*)(Wi + hj * NZ);
        float s = bi[hj];
#pragma unroll
        for (int k = 0; k < NZ / 4; ++k) {
            const float4 a = w4[k], z = zr[k];
            s += z.x * a.x + z.y * a.y + z.z * a.z + z.w * a.w;
        }
        const float e2 = __expf(2.f * s);
        const float th = 1.f - 2.f / (e2 + 1.f);
        h32d[(size_t)b * NH + jb * 16 + hj] = th;
        h16d[(size_t)b * NH + jb * 16 + hj] = (f16)th;
    }
}

// ---------------------------------------------------------------------------
extern "C" void kernel_launch(void* const* d_in, const int* in_sizes, int n_in,
                              void* d_out, int out_size, void* d_ws, size_t ws_size,
                              hipStream_t stream)
{
    const float* x     = (const float*)d_in[0];
    const float* noise = (const float*)d_in[1];
    const float* Wihf  = (const float*)d_in[2];
    const float* Whhf  = (const float*)d_in[3];
    const float* bihf  = (const float*)d_in[4];
    const float* bhhf  = (const float*)d_in[5];
    const float* Wihb  = (const float*)d_in[6];
    const float* Whhb  = (const float*)d_in[7];
    const float* bihb  = (const float*)d_in[8];
    const float* bhhb  = (const float*)d_in[9];
    const float* Wmu   = (const float*)d_in[10];
    const float* bmu   = (const float*)d_in[11];
    const float* Wvar  = (const float*)d_in[12];
    const float* bvar  = (const float*)d_in[13];
    const float* Winit = (const float*)d_in[14];
    const float* binit = (const float*)d_in[15];
    const float* Wo    = (const float*)d_in[16];
    const float* bo    = (const float*)d_in[17];
    const float* Wcih  = (const float*)d_in[18];
    const float* Wchh  = (const float*)d_in[19];
    const float* bcih  = (const float*)d_in[20];
    const float* bchh  = (const float*)d_in[21];
    float* dout = (float*)d_out;
    char*  ws   = (char*)d_ws;

    if (ws_size < WS_NEEDED) return;  // ~27.3 MB required

    f16* wmf  = (f16*)(ws + OFF_WMF);
    f16* wmb  = (f16*)(ws + OFF_WMB);
    f16* wmd  = (f16*)(ws + OFF_WMD);
    f16* wnf  = (f16*)(ws + OFF_WNF);
    f16* wnb  = (f16*)(ws + OFF_WNB);
    f16* wnd  = (f16*)(ws + OFF_WND);
    f16* wo16 = (f16*)(ws + OFF_WOUT);
    f16* henc16  = (f16*)(ws + OFF_HENC16);   // [dir][buf][NB*NH]
    float* hf32  = (float*)(ws + OFF_HF32);   // [dir][NB*NH]
    f16* hdec16  = (f16*)(ws + OFF_HDEC16);   // [buf][NB*NH]
    float* h32d  = (float*)(ws + OFF_H32D);
    float* z32p  = (float*)(ws + OFF_Z32);
    f16*   z16p  = (f16*)(ws + OFF_Z16);
    int*   cntb  = (int*)(ws + OFF_CNT);
    int* cnt_enc = cntb;
    int* cnt_dec = cntb + 2052;
    int* cnt_out = cntb + 3078;

    prep_kernel<<<2048, 256, 0, stream>>>(
        Whhf, Wihf, bihf, bhhf, Whhb, Wihb, bihb, bhhb,
        Wchh, Wcih, bcih, bchh, Wo, bo,
        wmf, wmb, wmd, wnf, wnb, wnd, wo16,
        henc16 /*dir0 buf0*/, henc16 + (size_t)2 * NB * NH /*dir1 buf0*/,
        cntb);

    // encoder: 512 steps in one persistent launch
    persist_kernel<0><<<256, 256, 0, stream>>>(
        x, wmf, wmb, wnf, wnb, (const f16*)nullptr, (const f16*)nullptr,
        henc16, hf32, (const float*)nullptr, dout, cnt_enc, (int*)nullptr);

    heads1_kernel<<<128, 256, 0, stream>>>(hf32, hf32 + (size_t)NB * NH,
                                           Wmu, bmu, Wvar, bvar, noise,
                                           dout, z32p, z16p);
    heads2_kernel<<<64, 256, 0, stream>>>(z32p, Winit, binit, h32d, hdec16);

    // decoder: 512 steps + fused sigmoid out-head in one persistent launch
    persist_kernel<1><<<136, 256, 0, stream>>>(
        x, wmd, (const f16*)nullptr, wnd, (const f16*)nullptr, wo16, z16p,
        hdec16, (float*)nullptr, h32d, dout, cnt_dec, cnt_out);
}

// Round 6
// 13547.797 us; speedup vs baseline: 2.7182x; 2.4678x over previous
//
#include <hip/hip_runtime.h>
#include <cstdint>
#include <cstddef>

// ---------------------------------------------------------------------------
// PurifiedVAE persistent-RNN, round 6.
// enc: persist_kernel<0>, 256 WGs = 4 chains (2 dir x 2 batch-halves) x 64 WGs.
// dec: persist_kernel<1>, 128 producer WGs (2 chains x 64) + 8 out-head WGs.
// Weights LDS-resident all 512 steps; fp32 h master in registers.
// A-path (cross-WG h16): global_load_lds size=4, aux=17 (SC0|SC1 -> LLC-
// coherent DMA into LDS), 16-chunk double-buffered K-loop, per-wave private
// blocks (no intra-K barriers), plain `s_waitcnt vmcnt(N)` with "memory"
// clobber (no register ties -- r4/r5's register-in-flight hazard is gone).
// ROOT-CAUSE FIX vs r4/r5: restored the Zx zero-init (quads 2-3 of the ext
// MFMA read Zx halves 16..31, which staging never writes -> was NaN source).
// Sync: per-WG one-shot flag slots (value = step+1), wave-parallel polling.
// ---------------------------------------------------------------------------

typedef _Float16 f16;
typedef _Float16 f16x8 __attribute__((ext_vector_type(8)));
typedef float f32x4 __attribute__((ext_vector_type(4)));

#define NB 256
#define NT 512
#define NI 12
#define NH 1024
#define NZ 128
#define NG 3072
#define KE_ENC 1056   // 1024 + 32 ext (x,1,pad)
#define KE_DEC 1184   // 1024 + 160 ext (x,1,pad,z128)
#define XK_ENC 32
#define XK_DEC 160

#define MFMA16(a, b, c) __builtin_amdgcn_mfma_f32_16x16x32_f16((a), (b), (c), 0, 0, 0)

// ---- workspace layout (bytes) ----
#define OFF_WMF   ((size_t)0)
#define OFF_WMB   (OFF_WMF + (size_t)NG * KE_ENC * 2)
#define OFF_WMD   (OFF_WMB + (size_t)NG * KE_ENC * 2)
#define OFF_WNF   (OFF_WMD + (size_t)NG * KE_DEC * 2)
#define OFF_WNB   (OFF_WNF + (size_t)NH * XK_ENC * 2)
#define OFF_WND   (OFF_WNB + (size_t)NH * XK_ENC * 2)
#define OFF_WOUT  (OFF_WND + (size_t)NH * XK_DEC * 2)
#define OFF_HENC16 (OFF_WOUT + (size_t)16 * KE_ENC * 2)   // [2 dir][2 buf][NB*NH] f16
#define OFF_HF32   (OFF_HENC16 + (size_t)4 * NB * NH * 2) // [2 dir][NB*NH] f32
#define OFF_HDEC16 (OFF_HF32 + (size_t)2 * NB * NH * 4)   // [2 buf][NB*NH] f16
#define OFF_H32D   (OFF_HDEC16 + (size_t)2 * NB * NH * 2) // [NB*NH] f32
#define OFF_Z32    (OFF_H32D + (size_t)NB * NH * 4)
#define OFF_Z16    (OFF_Z32 + (size_t)NB * NZ * 4)
#define OFF_FLG    (OFF_Z16 + (size_t)NB * NZ * 2)
// flags: enc 4*512*64 | dec 2*512*64 | out 2*512*8  = 204800 u32
#define N_FLG 204800
#define WS_NEEDED (OFF_FLG + (size_t)N_FLG * 4)

// d_out element offsets (fp32): recon [256,512,12], mean [256,128], stddev [256,128]
#define OUT_MEAN (NB * NT * NI)
#define OUT_STD  (OUT_MEAN + NB * NZ)

// LDS A-staging geometry: chunk = 64 k-halves x 128 rows, stored as 64
// row-pair blocks of 256 B at 272 B stride (pad 16 -> bank-balanced b128).
#define ABLK 272
#define ACHUNK (64 * ABLK)        // 17408 B per buffer (producer)

// whole-wave flag poll: lanes watch nslots (power of 2) slots in parallel.
__device__ __forceinline__ void wave_spin(const unsigned* base, unsigned tgt,
                                          int lane, int nslots) {
    const unsigned* p = base + (lane & (nslots - 1));
    for (;;) {
        unsigned v = __hip_atomic_load(p, __ATOMIC_RELAXED, __HIP_MEMORY_SCOPE_AGENT);
        if (__all((int)(v == tgt))) break;
        __builtin_amdgcn_s_sleep(1);
    }
}

// LLC-coherent global->LDS DMA, 4 B/lane (lane-contiguous 256 B block).
// aux = 17 = SC0|SC1 on gfx950 (system-scope: bypass L1+L2, serve from LLC).
__device__ __forceinline__ void dma4(const void* g, void* l) {
    __builtin_amdgcn_global_load_lds(
        (const __attribute__((address_space(1))) void*)g,
        (__attribute__((address_space(3))) void*)l, 4, 0, 17);
}

template<int N> __device__ __forceinline__ void waitv() {
    asm volatile("s_waitcnt vmcnt(%0)" :: "n"(N) : "memory");
}

// ---------------------------------------------------------------------------
// prep: build fp16 extended weight matrices, zero initial enc h16 buffers,
// zero flag arrays. (extended-K layout: see earlier rounds; unchanged)
// ---------------------------------------------------------------------------
__global__ __launch_bounds__(256) void prep_kernel(
    const float* __restrict__ Whhf, const float* __restrict__ Wihf,
    const float* __restrict__ bihf, const float* __restrict__ bhhf,
    const float* __restrict__ Whhb, const float* __restrict__ Wihb,
    const float* __restrict__ bihb, const float* __restrict__ bhhb,
    const float* __restrict__ Wchh, const float* __restrict__ Wcih,
    const float* __restrict__ bcih, const float* __restrict__ bchh,
    const float* __restrict__ Wo,   const float* __restrict__ bo,
    f16* __restrict__ wmf, f16* __restrict__ wmb, f16* __restrict__ wmd,
    f16* __restrict__ wnf, f16* __restrict__ wnb, f16* __restrict__ wnd,
    f16* __restrict__ wout,
    f16* __restrict__ h16e0f, f16* __restrict__ h16e0b,
    unsigned* __restrict__ flgs)
{
    const int gsz = gridDim.x * blockDim.x;
    const int gid = blockIdx.x * blockDim.x + threadIdx.x;

    for (int idx = gid; idx < NG * KE_ENC; idx += gsz) {
        const int c = idx / KE_ENC, k = idx - c * KE_ENC;
        float vf, vb;
        if (k < NH) { vf = Whhf[c * NH + k]; vb = Whhb[c * NH + k]; }
        else {
            const int e = k - NH;
            if (c < 2 * NH) {
                if (e < 12)       { vf = Wihf[c * 12 + e]; vb = Wihb[c * 12 + e]; }
                else if (e == 12) { vf = bihf[c] + bhhf[c]; vb = bihb[c] + bhhb[c]; }
                else              { vf = 0.f; vb = 0.f; }
            } else {
                vf = (e == 12) ? bhhf[c] : 0.f;
                vb = (e == 12) ? bhhb[c] : 0.f;
            }
        }
        wmf[idx] = (f16)vf; wmb[idx] = (f16)vb;
    }
    for (int idx = gid; idx < NG * KE_DEC; idx += gsz) {
        const int c = idx / KE_DEC, k = idx - c * KE_DEC;
        float v;
        if (k < NH) v = Wchh[c * NH + k];
        else {
            const int e = k - NH;
            if (c < 2 * NH) {
                if (e < 12)       v = Wcih[c * 140 + e];
                else if (e == 12) v = bcih[c] + bchh[c];
                else if (e < 32)  v = 0.f;
                else              v = Wcih[c * 140 + 12 + (e - 32)];
            } else v = (e == 12) ? bchh[c] : 0.f;
        }
        wmd[idx] = (f16)v;
    }
    for (int idx = gid; idx < NH * XK_ENC; idx += gsz) {
        const int j = idx >> 5, e = idx & 31;
        const int c = 2 * NH + j;
        float vf, vb;
        if (e < 12)       { vf = Wihf[c * 12 + e]; vb = Wihb[c * 12 + e]; }
        else if (e == 12) { vf = bihf[c]; vb = bihb[c]; }
        else              { vf = 0.f; vb = 0.f; }
        wnf[idx] = (f16)vf; wnb[idx] = (f16)vb;
    }
    for (int idx = gid; idx < NH * XK_DEC; idx += gsz) {
        const int j = idx / XK_DEC, e = idx - j * XK_DEC;
        const int c = 2 * NH + j;
        float v;
        if (e < 12)       v = Wcih[c * 140 + e];
        else if (e == 12) v = bcih[c];
        else if (e < 32)  v = 0.f;
        else              v = Wcih[c * 140 + 12 + (e - 32)];
        wnd[idx] = (f16)v;
    }
    for (int idx = gid; idx < 16 * KE_ENC; idx += gsz) {
        const int i = idx / KE_ENC, k = idx - i * KE_ENC;
        float v = 0.f;
        if (i < 12) {
            if (k < NH) v = Wo[i * NH + k];
            else if (k == NH + 12) v = bo[i];
        }
        wout[idx] = (f16)v;
    }
    for (int idx = gid; idx < NB * NH; idx += gsz) {
        h16e0f[idx] = (f16)0.f; h16e0b[idx] = (f16)0.f;
    }
    for (int idx = gid; idx < N_FLG; idx += gsz) flgs[idx] = 0u;
}

// ---------------------------------------------------------------------------
// persist_kernel<MODE>: MODE 0 = encoder (grid 256), MODE 1 = decoder (grid 136).
// Producer WG: chain = bid>>6, slice = bid&63 -> 48 gate-cols {r,z,n} of 16
// h-cols, M=128 batch rows.  Waves M-split 32 rows (2 row-tiles); each wave
// DMA-stages exactly its own 16 row-pair blocks per chunk (no K-loop barriers).
// Out-head WGs (dec, bid>=128): 32 rows x 16 out-cols each, K=1024 wout + ext.
// ---------------------------------------------------------------------------
template<int MODE>
__global__ __launch_bounds__(256, 1) void persist_kernel(
    const float* __restrict__ x,
    const f16* __restrict__ wmF, const f16* __restrict__ wmB_,
    const f16* __restrict__ wnF, const f16* __restrict__ wnB_,
    const f16* __restrict__ wout, const f16* __restrict__ z16,
    f16* __restrict__ hbuf,          // enc: [dir][2][NB*NH]; dec: [2][NB*NH]
    float* __restrict__ hf32,        // enc final fp32 out [dir][NB*NH]
    const float* __restrict__ h32i,  // dec initial master (heads2)
    float* __restrict__ dout,
    unsigned* __restrict__ flg,      // enc [4][512][64] ; dec [2][512][64]
    unsigned* __restrict__ flg_out)  // dec [2][512][8]
{
    constexpr int KE  = MODE ? KE_DEC : KE_ENC;
    constexpr int KEP = KE + 8;
    constexpr int XK  = MODE ? XK_DEC : XK_ENC;
    constexpr int XKP = XK + 8;
    constexpr int NZT = MODE ? 4 : 0;   // z-register A k-tiles

    __shared__ f16 Wlds[48 * KEP];      // enc 102.1 KB / dec 114.4 KB
    __shared__ char Abuf[2 * ACHUNK];   // 34.8 KB A DMA double buffer
    __shared__ f16 Zx[128 * 32];        // 8 KB per-step x+bias A-ext rows
    __shared__ f16 wnlds[16 * XKP];     // gi_n ext weights

    const int tid = threadIdx.x;
    const int bid = blockIdx.x;
    const int w = tid >> 6, lane = tid & 63;
    const int lr = lane & 15, quad = lane >> 4;

    if (MODE == 1 && bid >= 128) {
        // ---------------- out-head consumer WGs ----------------
        const int oc = bid - 128;                 // 0..7
        const int ochain = oc >> 2;
        const int mbase = ochain * 128 + (oc & 3) * 32;
        for (int u = tid; u < 16 * 132; u += 256) {
            const int r = u / 132, kk = u - r * 132;
            *(uint4*)&Wlds[r * 1064 + kk * 8] =
                *(const uint4*)(wout + (size_t)r * KE_ENC + kk * 8);
        }
        __syncthreads();
        if (w >= 2) return;                       // 2 active waves (16 rows each)
        const int rb = mbase + w * 16;
        f16x8 ax;                                 // A-ext: 1.0 at e==12
#pragma unroll
        for (int j = 0; j < 8; ++j) ax[j] = (f16)0.f;
        if (quad == 1) ax[4] = (f16)1.f;
        // per-chunk LDS/addr bases (wave-private blocks)
        const int ard = (w * 8 + (lr >> 1)) * ABLK + (lr & 1) * 128 + quad * 16;
#pragma unroll 1
        for (int t = 0; t < NT; ++t) {
            wave_spin(flg + ((size_t)ochain * 512 + t) * 64, (unsigned)(t + 1),
                      lane, 64);
            const f16* hc = hbuf + (size_t)((t + 1) & 1) * (NB * NH);
            const char* gb = (const char*)(hc +
                (size_t)(rb + (lane >> 5)) * NH) + (lane & 31) * 4;
#define OISSUE(c) do { \
    const char* g_ = gb + (c) * 128; \
    char* l_ = Abuf + ((c) & 1) * 4352 + w * 2176; \
    _Pragma("unroll") \
    for (int i_ = 0; i_ < 8; ++i_) dma4(g_ + i_ * 4096, l_ + i_ * ABLK); } while (0)
#define OCONS(c) do { \
    _Pragma("unroll") \
    for (int kt2_ = 0; kt2_ < 2; ++kt2_) { \
        f16x8 a_ = *(const f16x8*)(Abuf + ((c) & 1) * 4352 + ard + kt2_ * 64); \
        f16x8 b_ = *(const f16x8*)(&Wlds[lr * 1064 + ((c) * 2 + kt2_) * 32 + (quad << 3)]); \
        accq = MFMA16(a_, b_, accq); } } while (0)
            f32x4 accq = {0.f, 0.f, 0.f, 0.f};
            OISSUE(0); OISSUE(1);
#pragma unroll
            for (int c = 0; c < 15; ++c) {
                waitv<8>();
                OCONS(c);
                if (c < 14) OISSUE(c + 2);
            }
            waitv<0>();
            // all hbuf reads landed in LDS: release the ping-pong buffer
            if (lane == 0)
                __hip_atomic_store(
                    &flg_out[((size_t)ochain * 512 + t) * 8 + (oc & 3) * 2 + w],
                    (unsigned)(t + 1), __ATOMIC_RELAXED, __HIP_MEMORY_SCOPE_AGENT);
            OCONS(15);
            {
                f16x8 b = *(const f16x8*)(&Wlds[lr * 1064 + 1024 + (quad << 3)]);
                accq = MFMA16(ax, b, accq);
            }
            if (lr < NI) {
#pragma unroll
                for (int r = 0; r < 4; ++r) {
                    const int b_ = rb + quad * 4 + r;
                    dout[(size_t)b_ * (NT * NI) + t * NI + lr] =
                        1.f / (1.f + __expf(-accq[r]));
                }
            }
#undef OISSUE
#undef OCONS
        }
        return;
    }

    // ---------------- producer WGs ----------------
    const int chain = bid >> 6;                 // enc 0..3, dec 0..1
    const int slice = bid & 63;
    const int dir = MODE ? 0 : (chain >> 1);
    const int m0 = MODE ? chain * 128 : (chain & 1) * 128;
    const int j0 = slice * 16;

    const f16* wm = (MODE == 0 && dir) ? wmB_ : wmF;
    const f16* wn = (MODE == 0 && dir) ? wnB_ : wnF;
    f16* hb0 = hbuf + (MODE ? (size_t)0 : (size_t)dir * 2 * NB * NH);

    // one-time weight load into LDS + Zx zero-init (halves 16..31 stay 0!)
    constexpr int KQ = KE / 8;
    for (int u = tid; u < 48 * KQ; u += 256) {
        const int r = u / KQ, kk = u - r * KQ;
        const int c = (r >> 4) * NH + j0 + (r & 15);
        *(uint4*)&Wlds[r * KEP + kk * 8] = *(const uint4*)(wm + (size_t)c * KE + kk * 8);
    }
    constexpr int XQ = XK / 8;
    for (int u = tid; u < 16 * XQ; u += 256) {
        const int r = u / XQ, kk = u - r * XQ;
        *(uint4*)&wnlds[r * XKP + kk * 8] =
            *(const uint4*)(wn + (size_t)(j0 + r) * XK + kk * 8);
    }
    for (int u = tid; u < 128 * 32 / 8; u += 256)
        *(uint4*)&Zx[u * 8] = make_uint4(0u, 0u, 0u, 0u);
    __syncthreads();

    // register-resident fp32 h master + constant z A-fragments
    float hmast[2][4];
    f16x8 azr[2][NZT ? NZT : 1];
#pragma unroll
    for (int rt = 0; rt < 2; ++rt)
#pragma unroll
        for (int r = 0; r < 4; ++r)
            hmast[rt][r] = MODE
                ? h32i[(size_t)(m0 + (w << 5) + rt * 16 + quad * 4 + r) * NH + j0 + lr]
                : 0.f;
    if (MODE) {
#pragma unroll
        for (int rt = 0; rt < 2; ++rt)
#pragma unroll
            for (int zt = 0; zt < NZT; ++zt)
                azr[rt][zt] = *(const f16x8*)(z16 +
                    (size_t)(m0 + (w << 5) + rt * 16 + lr) * NZ + zt * 32 + (quad << 3));
    }

    unsigned* myflg = flg + (size_t)chain * 512 * 64;
    // A-read LDS offsets (bytes): wave-private blocks, rt-tile pair
    const int ard0 = (w * 16 + (lr >> 1)) * ABLK + (lr & 1) * 128 + quad * 16;
    const int ard1 = ard0 + 8 * ABLK;   // rt=1 -> +8 blocks

#pragma unroll 1
    for (int t = 0; t < NT; ++t) {
        // stage per-step A-ext rows (x teacher / x_t, bias 1 at e==12)
        if (tid < 128) {
            f16 rowv[16];
            if (MODE == 1 && t == 0) {
#pragma unroll
                for (int e = 0; e < 12; ++e) rowv[e] = (f16)((e == NI - 1) ? 1.f : 0.f);
            } else {
                const int b_ = m0 + tid;
                const int tx = MODE ? (t - 1) : (dir ? (NT - 1 - t) : t);
                const float4* xr = (const float4*)(x + ((size_t)b_ * NT + tx) * NI);
                const float4 x0 = xr[0], x1 = xr[1], x2 = xr[2];
                rowv[0] = (f16)x0.x; rowv[1] = (f16)x0.y; rowv[2] = (f16)x0.z; rowv[3] = (f16)x0.w;
                rowv[4] = (f16)x1.x; rowv[5] = (f16)x1.y; rowv[6] = (f16)x1.z; rowv[7] = (f16)x1.w;
                rowv[8] = (f16)x2.x; rowv[9] = (f16)x2.y; rowv[10] = (f16)x2.z; rowv[11] = (f16)x2.w;
            }
            rowv[12] = (f16)1.f; rowv[13] = (f16)0.f; rowv[14] = (f16)0.f; rowv[15] = (f16)0.f;
            *(uint4*)&Zx[tid * 32]     = *(const uint4*)&rowv[0];
            *(uint4*)&Zx[tid * 32 + 8] = *(const uint4*)&rowv[8];
        }
        // wait for step t-1 completion of all 64 slices (wave 0 polls)
        if (t > 0 && tid < 64)
            wave_spin(myflg + (size_t)(t - 1) * 64, (unsigned)t, lane, 64);
        __syncthreads();
        // protect ping-pong buffer from in-flight out-head readers (dec);
        // placed BEFORE the DMA window so no atomic ops disturb vmcnt.
        if (MODE == 1 && t >= 2) {
            if (tid < 64)
                wave_spin(flg_out + ((size_t)chain * 512 + (t - 2)) * 8,
                          (unsigned)(t - 1), lane, 8);
            __syncthreads();
        }

        const f16* hcur = hb0 + (size_t)(t & 1) * (NB * NH);
        const char* gb = (const char*)(hcur +
            (size_t)(m0 + (w << 5) + (lane >> 5)) * NH) + (lane & 31) * 4;

        f32x4 acc[3][2], accn[2];
#pragma unroll
        for (int g = 0; g < 3; ++g)
#pragma unroll
            for (int rt = 0; rt < 2; ++rt) { f32x4 zv = {0.f,0.f,0.f,0.f}; acc[g][rt] = zv; }
        { f32x4 zv = {0.f,0.f,0.f,0.f}; accn[0] = zv; accn[1] = zv; }

#define PISSUE(c) do { \
    const char* g_ = gb + (c) * 128; \
    char* l_ = Abuf + ((c) & 1) * ACHUNK + w * (16 * ABLK); \
    _Pragma("unroll") \
    for (int i_ = 0; i_ < 16; ++i_) dma4(g_ + i_ * 4096, l_ + i_ * ABLK); } while (0)
#define PCONS(c) do { \
    _Pragma("unroll") \
    for (int kt2_ = 0; kt2_ < 2; ++kt2_) { \
        const int ktg_ = (c) * 2 + kt2_; \
        f16x8 a0_ = *(const f16x8*)(Abuf + ((c) & 1) * ACHUNK + ard0 + kt2_ * 64); \
        f16x8 a1_ = *(const f16x8*)(Abuf + ((c) & 1) * ACHUNK + ard1 + kt2_ * 64); \
        _Pragma("unroll") \
        for (int g_ = 0; g_ < 3; ++g_) { \
            f16x8 b_ = *(const f16x8*)(&Wlds[(g_ * 16 + lr) * KEP + ktg_ * 32 + (quad << 3)]); \
            acc[g_][0] = MFMA16(a0_, b_, acc[g_][0]); \
            acc[g_][1] = MFMA16(a1_, b_, acc[g_][1]); } } } while (0)

        // 16-chunk double-buffered K-loop; each wave's blocks are private, so
        // no barriers -- only per-wave vmcnt pipelining.
        PISSUE(0); PISSUE(1);
#pragma unroll
        for (int c = 0; c < 15; ++c) {
            waitv<16>();
            PCONS(c);
            if (c < 14) PISSUE(c + 2);
        }
        waitv<0>();
        PCONS(15);
#undef PISSUE
#undef PCONS

        // ext K tiles: xt=0 -> Zx (x,bias); xt>=1 -> z registers (dec)
#pragma unroll
        for (int xt = 0; xt <= NZT; ++xt) {
            const int kt = 32 + xt;
            f16x8 a0, a1;
            if (xt == 0) {
                a0 = *(const f16x8*)(&Zx[((w << 5) + lr) * 32 + (quad << 3)]);
                a1 = *(const f16x8*)(&Zx[((w << 5) + 16 + lr) * 32 + (quad << 3)]);
            } else { a0 = azr[0][xt - 1]; a1 = azr[1][xt - 1]; }
#pragma unroll
            for (int g = 0; g < 3; ++g) {
                f16x8 b = *(const f16x8*)(&Wlds[(g * 16 + lr) * KEP + kt * 32 + (quad << 3)]);
                acc[g][0] = MFMA16(a0, b, acc[g][0]);
                acc[g][1] = MFMA16(a1, b, acc[g][1]);
            }
            f16x8 bn = *(const f16x8*)(&wnlds[lr * XKP + xt * 32 + (quad << 3)]);
            accn[0] = MFMA16(a0, bn, accn[0]);
            accn[1] = MFMA16(a1, bn, accn[1]);
        }

        // gate combine + h update (fp32 master in registers); h16 published
        // via packed write-through dword stores (column pairs via shfl_xor)
        f16* hnext = hb0 + (size_t)((t + 1) & 1) * (NB * NH);
#pragma unroll
        for (int rt = 0; rt < 2; ++rt) {
#pragma unroll
            for (int r = 0; r < 4; ++r) {
                const float rr  = acc[0][rt][r];
                const float zz  = acc[1][rt][r];
                const float ghn = acc[2][rt][r];
                const float gin = accn[rt][r];
                const float rg = 1.f / (1.f + __expf(-rr));
                const float zg = 1.f / (1.f + __expf(-zz));
                const float nv = gin + rg * ghn;
                const float e2 = __expf(2.f * nv);
                const float th = 1.f - 2.f / (e2 + 1.f);   // tanh, inf-safe
                const float hn = (1.f - zg) * th + zg * hmast[rt][r];
                hmast[rt][r] = hn;
                const unsigned hv =
                    (unsigned)__builtin_bit_cast(unsigned short, (f16)hn);
                const unsigned ov = (unsigned)__shfl_xor((int)hv, 1, 64);
                if (!(lr & 1)) {
                    const int row = m0 + (w << 5) + rt * 16 + quad * 4 + r;
                    __hip_atomic_store(
                        (unsigned*)&hnext[(size_t)row * NH + j0 + lr],
                        hv | (ov << 16),
                        __ATOMIC_RELAXED, __HIP_MEMORY_SCOPE_AGENT);
                }
            }
        }
        __syncthreads();   // vmcnt(0) drain of all waves' stores before flag
        if (tid == 0)
            __hip_atomic_store(myflg + (size_t)t * 64 + slice, (unsigned)(t + 1),
                               __ATOMIC_RELAXED, __HIP_MEMORY_SCOPE_AGENT);
    }

    if (MODE == 0) {
        float* hdst = hf32 + (size_t)dir * NB * NH;
#pragma unroll
        for (int rt = 0; rt < 2; ++rt)
#pragma unroll
            for (int r = 0; r < 4; ++r) {
                const int row = m0 + (w << 5) + rt * 16 + quad * 4 + r;
                hdst[(size_t)row * NH + j0 + lr] = hmast[rt][r];
            }
    }
}

// ---------------------------------------------------------------------------
// heads1: mean / stddev / z from final encoder states (fp32 exact).
// ---------------------------------------------------------------------------
__global__ __launch_bounds__(256) void heads1_kernel(
    const float* __restrict__ hf, const float* __restrict__ hb,
    const float* __restrict__ Wmu, const float* __restrict__ bmu,
    const float* __restrict__ Wvar, const float* __restrict__ bvar,
    const float* __restrict__ noise,
    float* __restrict__ dout, float* __restrict__ z32, f16* __restrict__ z16)
{
    const int tid = threadIdx.x;
    const int b  = ((int)blockIdx.x >> 3) * 16 + (tid >> 4);
    const int zi = ((int)blockIdx.x & 7) * 16 + (tid & 15);
    const float4* h4 = (const float4*)(hf + (size_t)b * NH);
    const float4* g4 = (const float4*)(hb + (size_t)b * NH);
    const float4* m4 = (const float4*)(Wmu + (size_t)zi * (2 * NH));
    const float4* v4 = (const float4*)(Wvar + (size_t)zi * (2 * NH));
    float sm_ = 0.f, sv = 0.f;
    for (int k = 0; k < NH / 4; ++k) {
        const float4 h = h4[k], a = m4[k], c = v4[k];
        sm_ += h.x * a.x + h.y * a.y + h.z * a.z + h.w * a.w;
        sv  += h.x * c.x + h.y * c.y + h.z * c.z + h.w * c.w;
    }
    for (int k = 0; k < NH / 4; ++k) {
        const float4 h = g4[k], a = m4[NH / 4 + k], c = v4[NH / 4 + k];
        sm_ += h.x * a.x + h.y * a.y + h.z * a.z + h.w * a.w;
        sv  += h.x * c.x + h.y * c.y + h.z * c.z + h.w * c.w;
    }
    const float mean = sm_ + bmu[zi];
    const float lv   = sv + bvar[zi];
    const float sd   = __expf(0.5f * lv);
    const float zv   = mean + sd * noise[(size_t)b * NZ + zi];
    dout[OUT_MEAN + (size_t)b * NZ + zi] = mean;
    dout[OUT_STD  + (size_t)b * NZ + zi] = sd;
    z32[b * NZ + zi] = zv;
    z16[b * NZ + zi] = (f16)zv;
}

// ---------------------------------------------------------------------------
// heads2: h_dec0 = tanh(z @ W_init^T + b_init) -> fp32 master + h16 buffer 0.
// ---------------------------------------------------------------------------
__global__ __launch_bounds__(256) void heads2_kernel(
    const float* __restrict__ z32, const float* __restrict__ Winit,
    const float* __restrict__ binit,
    float* __restrict__ h32d, f16* __restrict__ h16d)
{
    __shared__ float Wi[16 * NZ];
    __shared__ float bi[16];
    const int tid = threadIdx.x;
    const int jb = blockIdx.x;
    for (int f = tid; f < 16 * NZ; f += 256)
        Wi[f] = Winit[(size_t)(jb * 16 + (f >> 7)) * NZ + (f & 127)];
    if (tid < 16) bi[tid] = binit[jb * 16 + tid];
    __syncthreads();
    const int b = tid;
    const float4* z4 = (const float4*)(z32 + (size_t)b * NZ);
    float4 zr[NZ / 4];
#pragma unroll
    for (int k = 0; k < NZ / 4; ++k) zr[k] = z4[k];
    for (int hj = 0; hj < 16; ++hj) {
        const float4* w4 = (const float4*)(Wi + hj * NZ);
        float s = bi[hj];
#pragma unroll
        for (int k = 0; k < NZ / 4; ++k) {
            const float4 a = w4[k], z = zr[k];
            s += z.x * a.x + z.y * a.y + z.z * a.z + z.w * a.w;
        }
        const float e2 = __expf(2.f * s);
        const float th = 1.f - 2.f / (e2 + 1.f);
        h32d[(size_t)b * NH + jb * 16 + hj] = th;
        h16d[(size_t)b * NH + jb * 16 + hj] = (f16)th;
    }
}

// ---------------------------------------------------------------------------
extern "C" void kernel_launch(void* const* d_in, const int* in_sizes, int n_in,
                              void* d_out, int out_size, void* d_ws, size_t ws_size,
                              hipStream_t stream)
{
    const float* x     = (const float*)d_in[0];
    const float* noise = (const float*)d_in[1];
    const float* Wihf  = (const float*)d_in[2];
    const float* Whhf  = (const float*)d_in[3];
    const float* bihf  = (const float*)d_in[4];
    const float* bhhf  = (const float*)d_in[5];
    const float* Wihb  = (const float*)d_in[6];
    const float* Whhb  = (const float*)d_in[7];
    const float* bihb  = (const float*)d_in[8];
    const float* bhhb  = (const float*)d_in[9];
    const float* Wmu   = (const float*)d_in[10];
    const float* bmu   = (const float*)d_in[11];
    const float* Wvar  = (const float*)d_in[12];
    const float* bvar  = (const float*)d_in[13];
    const float* Winit = (const float*)d_in[14];
    const float* binit = (const float*)d_in[15];
    const float* Wo    = (const float*)d_in[16];
    const float* bo    = (const float*)d_in[17];
    const float* Wcih  = (const float*)d_in[18];
    const float* Wchh  = (const float*)d_in[19];
    const float* bcih  = (const float*)d_in[20];
    const float* bchh  = (const float*)d_in[21];
    float* dout = (float*)d_out;
    char*  ws   = (char*)d_ws;

    if (ws_size < WS_NEEDED) return;  // ~27.5 MB required

    f16* wmf  = (f16*)(ws + OFF_WMF);
    f16* wmb  = (f16*)(ws + OFF_WMB);
    f16* wmd  = (f16*)(ws + OFF_WMD);
    f16* wnf  = (f16*)(ws + OFF_WNF);
    f16* wnb  = (f16*)(ws + OFF_WNB);
    f16* wnd  = (f16*)(ws + OFF_WND);
    f16* wo16 = (f16*)(ws + OFF_WOUT);
    f16* henc16  = (f16*)(ws + OFF_HENC16);   // [dir][buf][NB*NH]
    float* hf32  = (float*)(ws + OFF_HF32);   // [dir][NB*NH]
    f16* hdec16  = (f16*)(ws + OFF_HDEC16);   // [buf][NB*NH]
    float* h32d  = (float*)(ws + OFF_H32D);
    float* z32p  = (float*)(ws + OFF_Z32);
    f16*   z16p  = (f16*)(ws + OFF_Z16);
    unsigned* flgs  = (unsigned*)(ws + OFF_FLG);
    unsigned* flg_e = flgs;                 // 4*512*64
    unsigned* flg_d = flgs + 131072;        // 2*512*64
    unsigned* flg_o = flgs + 131072 + 65536;// 2*512*8

    prep_kernel<<<2048, 256, 0, stream>>>(
        Whhf, Wihf, bihf, bhhf, Whhb, Wihb, bihb, bhhb,
        Wchh, Wcih, bcih, bchh, Wo, bo,
        wmf, wmb, wmd, wnf, wnb, wnd, wo16,
        henc16 /*dir0 buf0*/, henc16 + (size_t)2 * NB * NH /*dir1 buf0*/,
        flgs);

    // encoder: 512 steps in one persistent launch
    persist_kernel<0><<<256, 256, 0, stream>>>(
        x, wmf, wmb, wnf, wnb, (const f16*)nullptr, (const f16*)nullptr,
        henc16, hf32, (const float*)nullptr, dout, flg_e, (unsigned*)nullptr);

    heads1_kernel<<<128, 256, 0, stream>>>(hf32, hf32 + (size_t)NB * NH,
                                           Wmu, bmu, Wvar, bvar, noise,
                                           dout, z32p, z16p);
    heads2_kernel<<<64, 256, 0, stream>>>(z32p, Winit, binit, h32d, hdec16);

    // decoder: 512 steps + fused sigmoid out-head in one persistent launch
    persist_kernel<1><<<136, 256, 0, stream>>>(
        x, wmd, (const f16*)nullptr, wnd, (const f16*)nullptr, wo16, z16p,
        hdec16, (float*)nullptr, h32d, dout, flg_d, flg_o);
}